// Round 16
// baseline (607.768 us; speedup 1.0000x reference)
//
#include <hip/hip_runtime.h>
#include <hip/hip_bf16.h>

#define N_NODES 50000
#define T_SEQ 24
#define D_IN 16
#define H_DIM 64
#define SD 9
#define E_EDGES 1600000
#define NUM_GRAPHS 500
#define NBLK 196   // ceil(50000/256)
#define LSTM_BLOCKS 3125

typedef _Float16 half8 __attribute__((ext_vector_type(8)));
typedef _Float16 half4 __attribute__((ext_vector_type(4)));
typedef float floatx4 __attribute__((ext_vector_type(4)));

__device__ __forceinline__ float fsig(float x) {
    return __fdividef(1.0f, 1.0f + __expf(-x));
}
__device__ __forceinline__ float ftanh(float x) {
    return 1.0f - __fdividef(2.0f, 1.0f + __expf(2.0f * x));
}

// ---------------------------------------------------------------------------
// MFMA LSTM + fused l1/GCN1-transform epilogue + EDGE HISTOGRAM prologue.
// (r14/r15 verified, unchanged.)
// ---------------------------------------------------------------------------
__global__ __launch_bounds__(256, 2) void lstm_mfma(
    const float* __restrict__ x,
    const float* __restrict__ W_ih, const float* __restrict__ W_hh,
    const float* __restrict__ b_ih, const float* __restrict__ b_hh,
    const float* __restrict__ Wc, const float* __restrict__ bc,
    const float* __restrict__ sdi,
    const int* __restrict__ ei, int* __restrict__ cnt,
    _Float16* __restrict__ m_out)
{
    __shared__ _Float16 smem[2048 + 24 * 16 * 16];
    _Float16* hb0 = smem;
    _Float16* hb1 = smem + 1024;
    _Float16* xbuf = smem + 2048;   // [t][n][d] f16, all 24 steps

    const int tid  = threadIdx.x;
    const int lane = tid & 63;
    const int w    = tid >> 6;      // wave id: unit quarter
    const int lr   = lane & 15;
    const int lg   = lane >> 4;
    const int nbase = blockIdx.x * 16;   // 3125 * 16 = 50000 exactly

    // ---- edge histogram prologue (overlaps the latency-bound recurrence) ----
    for (int e = blockIdx.x * 256 + tid; e < E_EDGES; e += LSTM_BLOCKS * 256) {
        const int c = ei[E_EDGES + e];
        if ((unsigned)c < N_NODES) atomicAdd(&cnt[c], 1);
    }

    // ---- B fragments: LSTM gate weights ----
    half8 bw[4][3];
    float bias[4];
#pragma unroll
    for (int ct = 0; ct < 4; ct++) {
        const int r = ct * 64 + w * 16 + lr;
        bias[ct] = b_ih[r] + b_hh[r];
#pragma unroll
        for (int kt = 0; kt < 2; kt++) {
            const float* p = W_hh + r * 64 + kt * 32 + 8 * lg;
            half8 f;
#pragma unroll
            for (int e = 0; e < 8; e++) f[e] = (_Float16)p[e];
            bw[ct][kt] = f;
        }
        half8 f = {(_Float16)0, (_Float16)0, (_Float16)0, (_Float16)0,
                   (_Float16)0, (_Float16)0, (_Float16)0, (_Float16)0};
        if (lg < 2) {
            const float* p = W_ih + r * 16 + 8 * lg;
#pragma unroll
            for (int e = 0; e < 8; e++) f[e] = (_Float16)p[e];
        }
        bw[ct][2] = f;
    }

    // ---- B fragments: Wc for the fused m-transform (feat = 16w + lr) ----
    half8 bwc[3];
    {
        const int fr = w * 16 + lr;
#pragma unroll
        for (int kt = 0; kt < 2; kt++) {
            const float* p = Wc + fr * 73 + kt * 32 + 8 * lg;
            half8 f;
#pragma unroll
            for (int e = 0; e < 8; e++) f[e] = (_Float16)p[e];
            bwc[kt] = f;
        }
        half8 f = {(_Float16)0, (_Float16)0, (_Float16)0, (_Float16)0,
                   (_Float16)0, (_Float16)0, (_Float16)0, (_Float16)0};
#pragma unroll
        for (int e = 0; e < 8; e++) {
            const int k2 = 8 * lg + e;
            if (k2 < 9) f[e] = (_Float16)Wc[fr * 73 + 64 + k2];
            else if (k2 == 9) f[e] = (_Float16)bc[fr];
        }
        bwc[2] = f;
    }

    // ---- stage x: 16 nodes * 384 floats = 1536 float4, coalesced ----
#pragma unroll
    for (int it = 0; it < 6; it++) {
        const int f4 = tid + it * 256;        // 0..1535
        const int fi = f4 * 4;
        const int n  = fi / 384;
        const int rem = fi - n * 384;
        const int t  = rem >> 4;
        const int d  = rem & 15;
        const float4 v = *reinterpret_cast<const float4*>(
            x + (size_t)(nbase + n) * 384 + rem);
        half4 hv = {(_Float16)v.x, (_Float16)v.y, (_Float16)v.z, (_Float16)v.w};
        *reinterpret_cast<half4*>(&xbuf[t * 256 + n * 16 + d]) = hv;
    }
    if (tid < 128) { ((int*)hb0)[tid] = 0; ((int*)hb0)[tid + 128] = 0; ((int*)hb0)[tid + 256] = 0; ((int*)hb0)[tid + 384] = 0; }

    const int u = w * 16 + lr;
    int ra[2];
#pragma unroll
    for (int kt = 0; kt < 2; kt++)
        ra[kt] = lr * 64 + 8 * ((4 * kt + lg) ^ (lr & 7));
    int woff[4];
#pragma unroll
    for (int j = 0; j < 4; j++) {
        const int nj = 4 * lg + j;
        woff[j] = nj * 64 + (u & 7) + 8 * ((u >> 3) ^ (nj & 7));
    }
    const int xro = lr * 16 + 8 * (lg & 1);

    float c_reg[4];
#pragma unroll
    for (int j = 0; j < 4; j++) c_reg[j] = 0.0f;

    __syncthreads();

    auto step = [&](int tl, _Float16* hR, _Float16* hW) {
        floatx4 acc[4];
#pragma unroll
        for (int ct = 0; ct < 4; ct++) {
            floatx4 a = {bias[ct], bias[ct], bias[ct], bias[ct]};
            acc[ct] = a;
        }
        const half8 ax = *reinterpret_cast<const half8*>(&xbuf[tl * 256 + xro]);
        const half8 ah0 = *reinterpret_cast<const half8*>(&hR[ra[0]]);
        const half8 ah1 = *reinterpret_cast<const half8*>(&hR[ra[1]]);
#pragma unroll
        for (int ct = 0; ct < 4; ct++)
            acc[ct] = __builtin_amdgcn_mfma_f32_16x16x32_f16(ah0, bw[ct][0], acc[ct], 0, 0, 0);
#pragma unroll
        for (int ct = 0; ct < 4; ct++)
            acc[ct] = __builtin_amdgcn_mfma_f32_16x16x32_f16(ah1, bw[ct][1], acc[ct], 0, 0, 0);
#pragma unroll
        for (int ct = 0; ct < 4; ct++)
            acc[ct] = __builtin_amdgcn_mfma_f32_16x16x32_f16(ax, bw[ct][2], acc[ct], 0, 0, 0);

#pragma unroll
        for (int j = 0; j < 4; j++) {
            const float ig = fsig(acc[0][j]);
            const float fg = fsig(acc[1][j]);
            const float gg = ftanh(acc[2][j]);
            const float og = fsig(acc[3][j]);
            const float cv = fg * c_reg[j] + ig * gg;
            c_reg[j] = cv;
            const float hv = og * ftanh(cv);
            hW[woff[j]] = (_Float16)hv;
        }
        __syncthreads();
    };

    for (int tb = 0; tb < 6; tb++) {
        const int t0 = tb * 4;
        step(t0 + 0, hb0, hb1);
        step(t0 + 1, hb1, hb0);
        step(t0 + 2, hb0, hb1);
        step(t0 + 3, hb1, hb0);   // final h lands in hb0
    }

    // ---- fused m-transform: m_raw^T[64,16] = Wc . [h; sdi; 1] (UNSCALED) ----
    half8 axs = {(_Float16)0, (_Float16)0, (_Float16)0, (_Float16)0,
                 (_Float16)0, (_Float16)0, (_Float16)0, (_Float16)0};
#pragma unroll
    for (int e = 0; e < 8; e++) {
        const int k2 = 8 * lg + e;
        if (k2 < 9) axs[e] = (_Float16)sdi[(size_t)(nbase + lr) * SD + k2];
        else if (k2 == 9) axs[e] = (_Float16)1.0f;
    }
    const half8 fh0 = *reinterpret_cast<const half8*>(&hb0[ra[0]]);
    const half8 fh1 = *reinterpret_cast<const half8*>(&hb0[ra[1]]);
    floatx4 am = {0.0f, 0.0f, 0.0f, 0.0f};
    am = __builtin_amdgcn_mfma_f32_16x16x32_f16(fh0, bwc[0], am, 0, 0, 0);
    am = __builtin_amdgcn_mfma_f32_16x16x32_f16(fh1, bwc[1], am, 0, 0, 0);
    am = __builtin_amdgcn_mfma_f32_16x16x32_f16(axs, bwc[2], am, 0, 0, 0);
#pragma unroll
    for (int j = 0; j < 4; j++) {
        const int gn = nbase + 4 * lg + j;          // D row = node
        m_out[(size_t)gn * 64 + u] = (_Float16)am[j];   // D col = feat u
    }
}

// ---------------------------------------------------------------------------
// CSR build: 3-phase parallel scan -> fill (histogram lives inside lstm_mfma)
// ---------------------------------------------------------------------------
__global__ __launch_bounds__(256) void scanA(const int* __restrict__ cnt,
                                             int* __restrict__ ptr,
                                             float* __restrict__ dis,
                                             int* __restrict__ bsum)
{
    __shared__ int wsum[4];
    const int tid = threadIdx.x, lane = tid & 63, wv = tid >> 6;
    const int i = blockIdx.x * 256 + tid;
    const int orig = (i < N_NODES) ? cnt[i] : 0;
    int v = orig;
#pragma unroll
    for (int d = 1; d < 64; d <<= 1) {
        int nb = __shfl_up(v, d, 64);
        if (lane >= d) v += nb;
    }
    if (lane == 63) wsum[wv] = v;
    __syncthreads();
    int woff = 0;
#pragma unroll
    for (int k = 0; k < 3; k++) if (k < wv) woff += wsum[k];
    if (i < N_NODES) {
        ptr[i] = woff + v - orig;
        dis[i] = rsqrtf((float)(orig + 1));
    }
    if (tid == 255) bsum[blockIdx.x] = woff + v;
}

__global__ __launch_bounds__(256) void scanB(const int* __restrict__ bsum,
                                             int* __restrict__ boff,
                                             int* __restrict__ ptr,
                                             float* __restrict__ gzero)
{
    __shared__ int wsum[4];
    const int tid = threadIdx.x, lane = tid & 63, wv = tid >> 6;
#pragma unroll
    for (int k = 0; k < 4; k++) gzero[tid + k * 256] = 0.0f;
    const int orig = (tid < NBLK) ? bsum[tid] : 0;
    int v = orig;
#pragma unroll
    for (int d = 1; d < 64; d <<= 1) {
        int nb = __shfl_up(v, d, 64);
        if (lane >= d) v += nb;
    }
    if (lane == 63) wsum[wv] = v;
    __syncthreads();
    int woff = 0;
#pragma unroll
    for (int k = 0; k < 3; k++) if (k < wv) woff += wsum[k];
    if (tid < NBLK) boff[tid] = woff + v - orig;
    if (tid == 255) ptr[N_NODES] = woff + v;
}

__global__ __launch_bounds__(256) void scanC(int* __restrict__ ptr,
                                             const int* __restrict__ boff,
                                             int* __restrict__ cursor)
{
    const int i = blockIdx.x * 256 + threadIdx.x;
    if (i < N_NODES) {
        const int p = ptr[i] + boff[blockIdx.x];
        ptr[i] = p;
        cursor[i] = p;
    }
}

__global__ void fill_csr(const int* __restrict__ ei, int* __restrict__ cursor,
                         int* __restrict__ csr)
{
    int e = blockIdx.x * 256 + threadIdx.x;
    if (e < E_EDGES) {
        int r = ei[e];
        int c = ei[E_EDGES + e];
        if ((unsigned)r < N_NODES && (unsigned)c < N_NODES) {
            int slot = atomicAdd(&cursor[c], 1);
            csr[slot] = r;
        }
    }
}

// ---------------------------------------------------------------------------
// Weight pre-combination: Wc = Wg1 @ W1  [64 x 73], bc = Wg1 @ l1_b  [64]
// ---------------------------------------------------------------------------
__global__ void combine_w(const float* __restrict__ g1W, const float* __restrict__ l1W,
                          const float* __restrict__ l1b,
                          float* __restrict__ Wc, float* __restrict__ bc)
{
    int idx = blockIdx.x * 256 + threadIdx.x;
    int o = idx / 74, j = idx - o * 74;
    if (o >= 64) return;
    float acc = 0.0f;
    if (j < 73) {
#pragma unroll 8
        for (int k = 0; k < 64; k++) acc += g1W[o * 64 + k] * l1W[k * 73 + j];
        Wc[o * 73 + j] = acc;
    } else {
#pragma unroll 8
        for (int k = 0; k < 64; k++) acc += g1W[o * 64 + k] * l1b[k];
        bc[o] = acc;
    }
}

// ---------------------------------------------------------------------------
// BLOCK-per-dst gather + GCN1 finalize + GCN2 transform.
// 4 waves split the dst's edge list (stride-4) -> 4x memory-level parallelism
// on the latency-bound row gathers; partials combined through 1KB LDS.
// ---------------------------------------------------------------------------
__global__ __launch_bounds__(256) void gatherfin1s2(
    const int* __restrict__ ptr, const int* __restrict__ csr,
    const _Float16* __restrict__ m, const float* __restrict__ dis,
    const float* __restrict__ b1, const float* __restrict__ W2,
    float* __restrict__ s2)
{
    __shared__ float part[4][64];
    const int dst = blockIdx.x;
    const int f = threadIdx.x & 63;
    const int wv = threadIdx.x >> 6;
    const int b = ptr[dst];
    const int e = ptr[dst + 1];
    float a0 = 0.0f, a1 = 0.0f;
    // wave wv handles edges b+wv, b+wv+4, ... (2-way ILP within wave)
    int i = b + wv;
    for (; i + 4 < e; i += 8) {
        const int s0 = csr[i];
        const int s1 = csr[i + 4];
        a0 += dis[s0] * (float)m[(size_t)s0 * 64 + f];
        a1 += dis[s1] * (float)m[(size_t)s1 * 64 + f];
    }
    if (i < e) { const int s = csr[i]; a0 += dis[s] * (float)m[(size_t)s * 64 + f]; }
    part[wv][f] = a0 + a1;
    __syncthreads();
    if (wv == 0) {
        const float dn = dis[dst];
        const float self = dn * (float)m[(size_t)dst * 64 + f];
        const float sum = (part[0][f] + part[1][f]) + (part[2][f] + part[3][f]);
        const float v = dn * (sum + self) + b1[f];
        const float z1 = v > 0.0f ? v : 0.0f;
        float p = z1 * W2[f];
#pragma unroll
        for (int off = 32; off >= 1; off >>= 1) p += __shfl_xor(p, off, 64);
        if (f == 0) s2[dst] = dn * p;
    }
}

// ---------------------------------------------------------------------------
// WAVE-per-dst layer-2 gather + pool: 64 lanes walk the edge list in
// parallel (avg deg 32 -> 1 iteration) + shuffle reduce.
// ---------------------------------------------------------------------------
__global__ __launch_bounds__(256) void gather2fin(
    const int* __restrict__ ptr, const int* __restrict__ csr,
    const float* __restrict__ s2, const float* __restrict__ dis,
    const float* __restrict__ b2, const int* __restrict__ batch,
    float* __restrict__ gsum, float* __restrict__ gcnt)
{
    const int n = (blockIdx.x * 256 + threadIdx.x) >> 6;
    const int lane = threadIdx.x & 63;
    if (n >= N_NODES) return;
    const int b = ptr[n];
    const int e = ptr[n + 1];
    float a = 0.0f;
    for (int i = b + lane; i < e; i += 64) a += s2[csr[i]];
#pragma unroll
    for (int off = 32; off >= 1; off >>= 1) a += __shfl_xor(a, off, 64);
    if (lane == 0) {
        const float z2 = dis[n] * (a + s2[n]) + b2[0];
        const int g = batch[n];
        if ((unsigned)g < NUM_GRAPHS) {
            atomicAdd(&gsum[g], z2);
            atomicAdd(&gcnt[g], 1.0f);
        }
    }
}

__global__ void pooldiv(const float* __restrict__ gsum, const float* __restrict__ gcnt,
                        float* __restrict__ out)
{
    int g = blockIdx.x * 256 + threadIdx.x;
    if (g < NUM_GRAPHS) out[g] = gsum[g] / fmaxf(gcnt[g], 1.0f);
}

// ---------------------------------------------------------------------------
extern "C" void kernel_launch(void* const* d_in, const int* in_sizes, int n_in,
                              void* d_out, int out_size, void* d_ws, size_t ws_size,
                              hipStream_t stream)
{
    const float* x     = (const float*)d_in[0];
    const float* sdi   = (const float*)d_in[1];
    const int*   ei    = (const int*)d_in[2];
    const int*   batch = (const int*)d_in[3];
    const float* W_ih  = (const float*)d_in[4];
    const float* W_hh  = (const float*)d_in[5];
    const float* b_ih  = (const float*)d_in[6];
    const float* b_hh  = (const float*)d_in[7];
    const float* l1_W  = (const float*)d_in[8];
    const float* l1_b  = (const float*)d_in[9];
    const float* g1_W  = (const float*)d_in[10];
    const float* g1_b  = (const float*)d_in[11];
    const float* g2_W  = (const float*)d_in[12];
    const float* g2_b  = (const float*)d_in[13];
    float* out = (float*)d_out;

    // workspace layout
    float* ws   = (float*)d_ws;
    _Float16* C16 = (_Float16*)(ws + 6400000);   // m_raw (f16, 6.4MB)
    float* dis  = ws + 9600000;
    float* s2   = dis + 50000;
    float* gsum = s2 + 50000;         // gsum(500)+gcnt(500)+pad zeroed by scanB
    float* gcnt = gsum + 500;
    int* cnt    = (int*)(gsum + 1024);
    int* ptr    = cnt + 50000;        // 50001 entries
    int* cursor = ptr + 50001;
    int* csr    = cursor + 50000;     // 1.6M entries
    float* Wc   = (float*)(csr + E_EDGES);
    float* bc   = Wc + 64 * 73;
    int* bsum   = (int*)(bc + 64);    // 196
    int* boff   = bsum + NBLK;        // 196

    const int edgeBlocks = (E_EDGES + 255) / 256;

    // 1. zero histogram; combined weights (lstm needs Wc/bc)
    hipMemsetAsync(cnt, 0, 50000 * sizeof(int), stream);
    combine_w<<<(64 * 74 + 255) / 256, 256, 0, stream>>>(g1_W, l1_W, l1_b, Wc, bc);

    // 2. LSTM + fused l1/GCN1 transform -> C16 (m_raw), histogram prologue
    lstm_mfma<<<LSTM_BLOCKS, 256, 0, stream>>>(x, W_ih, W_hh, b_ih, b_hh,
                                               Wc, bc, sdi, ei, cnt, C16);

    // 3. CSR scan chain + fill
    scanA<<<NBLK, 256, 0, stream>>>(cnt, ptr, dis, bsum);
    scanB<<<1, 256, 0, stream>>>(bsum, boff, ptr, gsum);
    scanC<<<NBLK, 256, 0, stream>>>(ptr, boff, cursor);
    fill_csr<<<edgeBlocks, 256, 0, stream>>>(ei, cursor, csr);

    // 4. block-per-dst gather + finalize + gcn2 transform: s2
    gatherfin1s2<<<N_NODES, 256, 0, stream>>>(ptr, csr, C16, dis, g1_b, g2_W, s2);

    // 5. wave-per-dst gather2 + pool
    gather2fin<<<(N_NODES + 3) / 4, 256, 0, stream>>>(ptr, csr, s2, dis, g2_b, batch, gsum, gcnt);
    pooldiv<<<2, 256, 0, stream>>>(gsum, gcnt, out);
}

// Round 17
// 483.360 us; speedup vs baseline: 1.2574x; 1.2574x over previous
//
#include <hip/hip_runtime.h>
#include <hip/hip_bf16.h>

#define N_NODES 50000
#define T_SEQ 24
#define D_IN 16
#define H_DIM 64
#define SD 9
#define E_EDGES 1600000
#define NUM_GRAPHS 500
#define NBLK 196   // ceil(50000/256)
#define LSTM_BLOCKS 3125

typedef _Float16 half8 __attribute__((ext_vector_type(8)));
typedef _Float16 half4 __attribute__((ext_vector_type(4)));
typedef float floatx4 __attribute__((ext_vector_type(4)));

__device__ __forceinline__ float fsig(float x) {
    return __fdividef(1.0f, 1.0f + __expf(-x));
}
__device__ __forceinline__ float ftanh(float x) {
    return 1.0f - __fdividef(2.0f, 1.0f + __expf(2.0f * x));
}

// ---------------------------------------------------------------------------
// MFMA LSTM + fused l1/GCN1-transform epilogue + EDGE HISTOGRAM prologue.
// (r15 verified configuration, 487us total -- r16's block-per-dst gather
// regressed +121us: 50K tiny blocks = dispatch overhead + idle lanes.)
// ---------------------------------------------------------------------------
__global__ __launch_bounds__(256, 2) void lstm_mfma(
    const float* __restrict__ x,
    const float* __restrict__ W_ih, const float* __restrict__ W_hh,
    const float* __restrict__ b_ih, const float* __restrict__ b_hh,
    const float* __restrict__ Wc, const float* __restrict__ bc,
    const float* __restrict__ sdi,
    const int* __restrict__ ei, int* __restrict__ cnt,
    _Float16* __restrict__ m_out)
{
    __shared__ _Float16 smem[2048 + 24 * 16 * 16];
    _Float16* hb0 = smem;
    _Float16* hb1 = smem + 1024;
    _Float16* xbuf = smem + 2048;   // [t][n][d] f16, all 24 steps

    const int tid  = threadIdx.x;
    const int lane = tid & 63;
    const int w    = tid >> 6;      // wave id: unit quarter
    const int lr   = lane & 15;
    const int lg   = lane >> 4;
    const int nbase = blockIdx.x * 16;   // 3125 * 16 = 50000 exactly

    // ---- edge histogram prologue (overlaps the latency-bound recurrence) ----
    for (int e = blockIdx.x * 256 + tid; e < E_EDGES; e += LSTM_BLOCKS * 256) {
        const int c = ei[E_EDGES + e];
        if ((unsigned)c < N_NODES) atomicAdd(&cnt[c], 1);
    }

    // ---- B fragments: LSTM gate weights ----
    half8 bw[4][3];
    float bias[4];
#pragma unroll
    for (int ct = 0; ct < 4; ct++) {
        const int r = ct * 64 + w * 16 + lr;
        bias[ct] = b_ih[r] + b_hh[r];
#pragma unroll
        for (int kt = 0; kt < 2; kt++) {
            const float* p = W_hh + r * 64 + kt * 32 + 8 * lg;
            half8 f;
#pragma unroll
            for (int e = 0; e < 8; e++) f[e] = (_Float16)p[e];
            bw[ct][kt] = f;
        }
        half8 f = {(_Float16)0, (_Float16)0, (_Float16)0, (_Float16)0,
                   (_Float16)0, (_Float16)0, (_Float16)0, (_Float16)0};
        if (lg < 2) {
            const float* p = W_ih + r * 16 + 8 * lg;
#pragma unroll
            for (int e = 0; e < 8; e++) f[e] = (_Float16)p[e];
        }
        bw[ct][2] = f;
    }

    // ---- B fragments: Wc for the fused m-transform (feat = 16w + lr) ----
    half8 bwc[3];
    {
        const int fr = w * 16 + lr;
#pragma unroll
        for (int kt = 0; kt < 2; kt++) {
            const float* p = Wc + fr * 73 + kt * 32 + 8 * lg;
            half8 f;
#pragma unroll
            for (int e = 0; e < 8; e++) f[e] = (_Float16)p[e];
            bwc[kt] = f;
        }
        half8 f = {(_Float16)0, (_Float16)0, (_Float16)0, (_Float16)0,
                   (_Float16)0, (_Float16)0, (_Float16)0, (_Float16)0};
#pragma unroll
        for (int e = 0; e < 8; e++) {
            const int k2 = 8 * lg + e;
            if (k2 < 9) f[e] = (_Float16)Wc[fr * 73 + 64 + k2];
            else if (k2 == 9) f[e] = (_Float16)bc[fr];
        }
        bwc[2] = f;
    }

    // ---- stage x: 16 nodes * 384 floats = 1536 float4, coalesced ----
#pragma unroll
    for (int it = 0; it < 6; it++) {
        const int f4 = tid + it * 256;        // 0..1535
        const int fi = f4 * 4;
        const int n  = fi / 384;
        const int rem = fi - n * 384;
        const int t  = rem >> 4;
        const int d  = rem & 15;
        const float4 v = *reinterpret_cast<const float4*>(
            x + (size_t)(nbase + n) * 384 + rem);
        half4 hv = {(_Float16)v.x, (_Float16)v.y, (_Float16)v.z, (_Float16)v.w};
        *reinterpret_cast<half4*>(&xbuf[t * 256 + n * 16 + d]) = hv;
    }
    if (tid < 128) { ((int*)hb0)[tid] = 0; ((int*)hb0)[tid + 128] = 0; ((int*)hb0)[tid + 256] = 0; ((int*)hb0)[tid + 384] = 0; }

    const int u = w * 16 + lr;
    int ra[2];
#pragma unroll
    for (int kt = 0; kt < 2; kt++)
        ra[kt] = lr * 64 + 8 * ((4 * kt + lg) ^ (lr & 7));
    int woff[4];
#pragma unroll
    for (int j = 0; j < 4; j++) {
        const int nj = 4 * lg + j;
        woff[j] = nj * 64 + (u & 7) + 8 * ((u >> 3) ^ (nj & 7));
    }
    const int xro = lr * 16 + 8 * (lg & 1);

    float c_reg[4];
#pragma unroll
    for (int j = 0; j < 4; j++) c_reg[j] = 0.0f;

    __syncthreads();

    auto step = [&](int tl, _Float16* hR, _Float16* hW) {
        floatx4 acc[4];
#pragma unroll
        for (int ct = 0; ct < 4; ct++) {
            floatx4 a = {bias[ct], bias[ct], bias[ct], bias[ct]};
            acc[ct] = a;
        }
        const half8 ax = *reinterpret_cast<const half8*>(&xbuf[tl * 256 + xro]);
        const half8 ah0 = *reinterpret_cast<const half8*>(&hR[ra[0]]);
        const half8 ah1 = *reinterpret_cast<const half8*>(&hR[ra[1]]);
#pragma unroll
        for (int ct = 0; ct < 4; ct++)
            acc[ct] = __builtin_amdgcn_mfma_f32_16x16x32_f16(ah0, bw[ct][0], acc[ct], 0, 0, 0);
#pragma unroll
        for (int ct = 0; ct < 4; ct++)
            acc[ct] = __builtin_amdgcn_mfma_f32_16x16x32_f16(ah1, bw[ct][1], acc[ct], 0, 0, 0);
#pragma unroll
        for (int ct = 0; ct < 4; ct++)
            acc[ct] = __builtin_amdgcn_mfma_f32_16x16x32_f16(ax, bw[ct][2], acc[ct], 0, 0, 0);

#pragma unroll
        for (int j = 0; j < 4; j++) {
            const float ig = fsig(acc[0][j]);
            const float fg = fsig(acc[1][j]);
            const float gg = ftanh(acc[2][j]);
            const float og = fsig(acc[3][j]);
            const float cv = fg * c_reg[j] + ig * gg;
            c_reg[j] = cv;
            const float hv = og * ftanh(cv);
            hW[woff[j]] = (_Float16)hv;
        }
        __syncthreads();
    };

    for (int tb = 0; tb < 6; tb++) {
        const int t0 = tb * 4;
        step(t0 + 0, hb0, hb1);
        step(t0 + 1, hb1, hb0);
        step(t0 + 2, hb0, hb1);
        step(t0 + 3, hb1, hb0);   // final h lands in hb0
    }

    // ---- fused m-transform: m_raw^T[64,16] = Wc . [h; sdi; 1] (UNSCALED) ----
    half8 axs = {(_Float16)0, (_Float16)0, (_Float16)0, (_Float16)0,
                 (_Float16)0, (_Float16)0, (_Float16)0, (_Float16)0};
#pragma unroll
    for (int e = 0; e < 8; e++) {
        const int k2 = 8 * lg + e;
        if (k2 < 9) axs[e] = (_Float16)sdi[(size_t)(nbase + lr) * SD + k2];
        else if (k2 == 9) axs[e] = (_Float16)1.0f;
    }
    const half8 fh0 = *reinterpret_cast<const half8*>(&hb0[ra[0]]);
    const half8 fh1 = *reinterpret_cast<const half8*>(&hb0[ra[1]]);
    floatx4 am = {0.0f, 0.0f, 0.0f, 0.0f};
    am = __builtin_amdgcn_mfma_f32_16x16x32_f16(fh0, bwc[0], am, 0, 0, 0);
    am = __builtin_amdgcn_mfma_f32_16x16x32_f16(fh1, bwc[1], am, 0, 0, 0);
    am = __builtin_amdgcn_mfma_f32_16x16x32_f16(axs, bwc[2], am, 0, 0, 0);
#pragma unroll
    for (int j = 0; j < 4; j++) {
        const int gn = nbase + 4 * lg + j;          // D row = node
        m_out[(size_t)gn * 64 + u] = (_Float16)am[j];   // D col = feat u
    }
}

// ---------------------------------------------------------------------------
// CSR build: 3-phase parallel scan -> fill (histogram lives inside lstm_mfma)
// ---------------------------------------------------------------------------
__global__ __launch_bounds__(256) void scanA(const int* __restrict__ cnt,
                                             int* __restrict__ ptr,
                                             float* __restrict__ dis,
                                             int* __restrict__ bsum)
{
    __shared__ int wsum[4];
    const int tid = threadIdx.x, lane = tid & 63, wv = tid >> 6;
    const int i = blockIdx.x * 256 + tid;
    const int orig = (i < N_NODES) ? cnt[i] : 0;
    int v = orig;
#pragma unroll
    for (int d = 1; d < 64; d <<= 1) {
        int nb = __shfl_up(v, d, 64);
        if (lane >= d) v += nb;
    }
    if (lane == 63) wsum[wv] = v;
    __syncthreads();
    int woff = 0;
#pragma unroll
    for (int k = 0; k < 3; k++) if (k < wv) woff += wsum[k];
    if (i < N_NODES) {
        ptr[i] = woff + v - orig;
        dis[i] = rsqrtf((float)(orig + 1));
    }
    if (tid == 255) bsum[blockIdx.x] = woff + v;
}

__global__ __launch_bounds__(256) void scanB(const int* __restrict__ bsum,
                                             int* __restrict__ boff,
                                             int* __restrict__ ptr,
                                             float* __restrict__ gzero)
{
    __shared__ int wsum[4];
    const int tid = threadIdx.x, lane = tid & 63, wv = tid >> 6;
#pragma unroll
    for (int k = 0; k < 4; k++) gzero[tid + k * 256] = 0.0f;
    const int orig = (tid < NBLK) ? bsum[tid] : 0;
    int v = orig;
#pragma unroll
    for (int d = 1; d < 64; d <<= 1) {
        int nb = __shfl_up(v, d, 64);
        if (lane >= d) v += nb;
    }
    if (lane == 63) wsum[wv] = v;
    __syncthreads();
    int woff = 0;
#pragma unroll
    for (int k = 0; k < 3; k++) if (k < wv) woff += wsum[k];
    if (tid < NBLK) boff[tid] = woff + v - orig;
    if (tid == 255) ptr[N_NODES] = woff + v;
}

__global__ __launch_bounds__(256) void scanC(int* __restrict__ ptr,
                                             const int* __restrict__ boff,
                                             int* __restrict__ cursor)
{
    const int i = blockIdx.x * 256 + threadIdx.x;
    if (i < N_NODES) {
        const int p = ptr[i] + boff[blockIdx.x];
        ptr[i] = p;
        cursor[i] = p;
    }
}

__global__ void fill_csr(const int* __restrict__ ei, int* __restrict__ cursor,
                         int* __restrict__ csr)
{
    int e = blockIdx.x * 256 + threadIdx.x;
    if (e < E_EDGES) {
        int r = ei[e];
        int c = ei[E_EDGES + e];
        if ((unsigned)r < N_NODES && (unsigned)c < N_NODES) {
            int slot = atomicAdd(&cursor[c], 1);
            csr[slot] = r;
        }
    }
}

// ---------------------------------------------------------------------------
// Weight pre-combination: Wc = Wg1 @ W1  [64 x 73], bc = Wg1 @ l1_b  [64]
// ---------------------------------------------------------------------------
__global__ void combine_w(const float* __restrict__ g1W, const float* __restrict__ l1W,
                          const float* __restrict__ l1b,
                          float* __restrict__ Wc, float* __restrict__ bc)
{
    int idx = blockIdx.x * 256 + threadIdx.x;
    int o = idx / 74, j = idx - o * 74;
    if (o >= 64) return;
    float acc = 0.0f;
    if (j < 73) {
#pragma unroll 8
        for (int k = 0; k < 64; k++) acc += g1W[o * 64 + k] * l1W[k * 73 + j];
        Wc[o * 73 + j] = acc;
    } else {
#pragma unroll 8
        for (int k = 0; k < 64; k++) acc += g1W[o * 64 + k] * l1b[k];
        bc[o] = acc;
    }
}

// ---------------------------------------------------------------------------
// fused gather(f16, unroll-8 MLP) + GCN1 finalize + GCN2 transform
// (r15 verified: wave-per-dst, 8 independent chains)
// ---------------------------------------------------------------------------
__global__ __launch_bounds__(256) void gatherfin1s2(
    const int* __restrict__ ptr, const int* __restrict__ csr,
    const _Float16* __restrict__ m, const float* __restrict__ dis,
    const float* __restrict__ b1, const float* __restrict__ W2,
    float* __restrict__ s2)
{
    const int wid = (blockIdx.x * 256 + threadIdx.x) >> 6;
    const int f = threadIdx.x & 63;
    if (wid >= N_NODES) return;
    const int b = ptr[wid];
    const int e = ptr[wid + 1];
    float a0 = 0.0f, a1 = 0.0f, a2 = 0.0f, a3 = 0.0f;
    float a4 = 0.0f, a5 = 0.0f, a6 = 0.0f, a7 = 0.0f;
    int i = b;
    for (; i + 8 <= e; i += 8) {
        const int s0 = csr[i],     s1 = csr[i + 1], s2i = csr[i + 2], s3 = csr[i + 3];
        const int s4 = csr[i + 4], s5 = csr[i + 5], s6 = csr[i + 6], s7 = csr[i + 7];
        a0 += dis[s0] * (float)m[(size_t)s0 * 64 + f];
        a1 += dis[s1] * (float)m[(size_t)s1 * 64 + f];
        a2 += dis[s2i] * (float)m[(size_t)s2i * 64 + f];
        a3 += dis[s3] * (float)m[(size_t)s3 * 64 + f];
        a4 += dis[s4] * (float)m[(size_t)s4 * 64 + f];
        a5 += dis[s5] * (float)m[(size_t)s5 * 64 + f];
        a6 += dis[s6] * (float)m[(size_t)s6 * 64 + f];
        a7 += dis[s7] * (float)m[(size_t)s7 * 64 + f];
    }
    for (; i < e; i++) { const int s = csr[i]; a0 += dis[s] * (float)m[(size_t)s * 64 + f]; }
    const float dn = dis[wid];
    const float self = dn * (float)m[(size_t)wid * 64 + f];
    const float v = dn * ((((a0 + a1) + (a2 + a3)) + ((a4 + a5) + (a6 + a7))) + self) + b1[f];
    const float z1 = v > 0.0f ? v : 0.0f;
    float p = z1 * W2[f];
#pragma unroll
    for (int off = 32; off >= 1; off >>= 1) p += __shfl_xor(p, off, 64);
    if (f == 0) s2[wid] = dn * p;
}

__global__ void gather2fin(const int* __restrict__ ptr, const int* __restrict__ csr,
                           const float* __restrict__ s2, const float* __restrict__ dis,
                           const float* __restrict__ b2, const int* __restrict__ batch,
                           float* __restrict__ gsum, float* __restrict__ gcnt)
{
    int n = blockIdx.x * 256 + threadIdx.x;
    if (n >= N_NODES) return;
    const int b = ptr[n];
    const int e = ptr[n + 1];
    float a0 = 0.0f, a1 = 0.0f, a2 = 0.0f, a3 = 0.0f;
    float a4 = 0.0f, a5 = 0.0f, a6 = 0.0f, a7 = 0.0f;
    int i = b;
    for (; i + 8 <= e; i += 8) {
        a0 += s2[csr[i]];
        a1 += s2[csr[i + 1]];
        a2 += s2[csr[i + 2]];
        a3 += s2[csr[i + 3]];
        a4 += s2[csr[i + 4]];
        a5 += s2[csr[i + 5]];
        a6 += s2[csr[i + 6]];
        a7 += s2[csr[i + 7]];
    }
    for (; i < e; i++) a0 += s2[csr[i]];
    const float z2 = dis[n] * ((((a0 + a1) + (a2 + a3)) + ((a4 + a5) + (a6 + a7))) + s2[n]) + b2[0];
    const int g = batch[n];
    if ((unsigned)g < NUM_GRAPHS) {
        atomicAdd(&gsum[g], z2);
        atomicAdd(&gcnt[g], 1.0f);
    }
}

__global__ void pooldiv(const float* __restrict__ gsum, const float* __restrict__ gcnt,
                        float* __restrict__ out)
{
    int g = blockIdx.x * 256 + threadIdx.x;
    if (g < NUM_GRAPHS) out[g] = gsum[g] / fmaxf(gcnt[g], 1.0f);
}

// ---------------------------------------------------------------------------
extern "C" void kernel_launch(void* const* d_in, const int* in_sizes, int n_in,
                              void* d_out, int out_size, void* d_ws, size_t ws_size,
                              hipStream_t stream)
{
    const float* x     = (const float*)d_in[0];
    const float* sdi   = (const float*)d_in[1];
    const int*   ei    = (const int*)d_in[2];
    const int*   batch = (const int*)d_in[3];
    const float* W_ih  = (const float*)d_in[4];
    const float* W_hh  = (const float*)d_in[5];
    const float* b_ih  = (const float*)d_in[6];
    const float* b_hh  = (const float*)d_in[7];
    const float* l1_W  = (const float*)d_in[8];
    const float* l1_b  = (const float*)d_in[9];
    const float* g1_W  = (const float*)d_in[10];
    const float* g1_b  = (const float*)d_in[11];
    const float* g2_W  = (const float*)d_in[12];
    const float* g2_b  = (const float*)d_in[13];
    float* out = (float*)d_out;

    // workspace layout
    float* ws   = (float*)d_ws;
    _Float16* C16 = (_Float16*)(ws + 6400000);   // m_raw (f16, 6.4MB)
    float* dis  = ws + 9600000;
    float* s2   = dis + 50000;
    float* gsum = s2 + 50000;         // gsum(500)+gcnt(500)+pad zeroed by scanB
    float* gcnt = gsum + 500;
    int* cnt    = (int*)(gsum + 1024);
    int* ptr    = cnt + 50000;        // 50001 entries
    int* cursor = ptr + 50001;
    int* csr    = cursor + 50000;     // 1.6M entries
    float* Wc   = (float*)(csr + E_EDGES);
    float* bc   = Wc + 64 * 73;
    int* bsum   = (int*)(bc + 64);    // 196
    int* boff   = bsum + NBLK;        // 196

    const int featBlocks = (N_NODES * 64 + 255) / 256;   // 12500
    const int edgeBlocks = (E_EDGES + 255) / 256;

    // 1. zero histogram; combined weights (lstm needs Wc/bc)
    hipMemsetAsync(cnt, 0, 50000 * sizeof(int), stream);
    combine_w<<<(64 * 74 + 255) / 256, 256, 0, stream>>>(g1_W, l1_W, l1_b, Wc, bc);

    // 2. LSTM + fused l1/GCN1 transform -> C16 (m_raw), histogram prologue
    lstm_mfma<<<LSTM_BLOCKS, 256, 0, stream>>>(x, W_ih, W_hh, b_ih, b_hh,
                                               Wc, bc, sdi, ei, cnt, C16);

    // 3. CSR scan chain + fill
    scanA<<<NBLK, 256, 0, stream>>>(cnt, ptr, dis, bsum);
    scanB<<<1, 256, 0, stream>>>(bsum, boff, ptr, gsum);
    scanC<<<NBLK, 256, 0, stream>>>(ptr, boff, cursor);
    fill_csr<<<edgeBlocks, 256, 0, stream>>>(ei, cursor, csr);

    // 4. fused gather + finalize + gcn2 transform: s2 (r15: wave-per-dst)
    gatherfin1s2<<<featBlocks, 256, 0, stream>>>(ptr, csr, C16, dis, g1_b, g2_W, s2);

    // 5. gather2 + pool (r15: thread-per-dst, unroll-8)
    gather2fin<<<NBLK, 256, 0, stream>>>(ptr, csr, s2, dis, g2_b, batch, gsum, gcnt);
    pooldiv<<<2, 256, 0, stream>>>(gsum, gcnt, out);
}